// Round 11
// baseline (3186.736 us; speedup 1.0000x reference)
//
#include <hip/hip_runtime.h>

#define LSEQ 512
#define NIN 1024
#define NH 2048
#define NV 50257
#define NG 8192  /* 4*NH */

typedef float f32x4 __attribute__((ext_vector_type(4)));
typedef short s16x8 __attribute__((ext_vector_type(8)));
typedef unsigned long long u64;

// ---------------------------------------------------------------------------
// fp32 -> bf16 RNE helper for the split-bf16 trick.
// ---------------------------------------------------------------------------
__device__ __forceinline__ unsigned short bf16_hi_rne(float x)
{
    unsigned u = __float_as_uint(x);
    return (unsigned short)((u + 0x7fffu + ((u >> 16) & 1u)) >> 16);
}

// ---------------------------------------------------------------------------
// 3-term split-bf16 MFMA GEMM (round-5 structure, proven):
// C = A@B^T + bias1 + bias2;  A.B ~= Ah.Bh + Ah.Bl + Al.Bh  (~fp32-class).
// ---------------------------------------------------------------------------
__global__ __launch_bounds__(256, 2)
void gemm_x3(const float* __restrict__ A, const float* __restrict__ B,
             const float* __restrict__ bias1, const float* __restrict__ bias2,
             float* __restrict__ C, int M, int N, int K)
{
    __shared__ unsigned short Ah[128 * 40], Al[128 * 40];
    __shared__ unsigned short Bh[128 * 40], Bl[128 * 40];

    const int tid  = threadIdx.x;
    const int m0   = blockIdx.x * 128;
    const int n0   = blockIdx.y * 128;
    const int lrow = tid >> 1;
    const int lk0  = (tid & 1) << 4;
    const int lane = tid & 63;
    const int wave = tid >> 6;
    const int wm   = (wave >> 1) * 64;
    const int wn   = (wave & 1) * 64;
    const int fr   = lane & 15;
    const int fk   = (lane >> 4) * 8;

    f32x4 acc[4][4];
#pragma unroll
    for (int i = 0; i < 4; ++i)
#pragma unroll
        for (int j = 0; j < 4; ++j) acc[i][j] = (f32x4){0.f, 0.f, 0.f, 0.f};

    const bool bvalid = (n0 + lrow) < N;
    const float* pa = A + (size_t)(m0 + lrow) * K + lk0;
    const float* pb = bvalid ? (B + (size_t)(n0 + lrow) * K + lk0) : nullptr;

    for (int k0 = 0; k0 < K; k0 += 32) {
        float4 va[4], vb[4];
#pragma unroll
        for (int q = 0; q < 4; ++q) va[q] = *(const float4*)(pa + k0 + 4 * q);
        if (bvalid) {
#pragma unroll
            for (int q = 0; q < 4; ++q) vb[q] = *(const float4*)(pb + k0 + 4 * q);
        } else {
#pragma unroll
            for (int q = 0; q < 4; ++q) vb[q] = make_float4(0.f, 0.f, 0.f, 0.f);
        }

#pragma unroll
        for (int q = 0; q < 4; ++q) {
            const float av[4] = {va[q].x, va[q].y, va[q].z, va[q].w};
            const float bv[4] = {vb[q].x, vb[q].y, vb[q].z, vb[q].w};
            ushort4 ah, alo, bh, blo;
            unsigned short* ahp = (unsigned short*)&ah;
            unsigned short* alp = (unsigned short*)&alo;
            unsigned short* bhp = (unsigned short*)&bh;
            unsigned short* blp = (unsigned short*)&blo;
#pragma unroll
            for (int j = 0; j < 4; ++j) {
                const unsigned short h = bf16_hi_rne(av[j]);
                ahp[j] = h;
                alp[j] = bf16_hi_rne(av[j] - __uint_as_float((unsigned)h << 16));
                const unsigned short g = bf16_hi_rne(bv[j]);
                bhp[j] = g;
                blp[j] = bf16_hi_rne(bv[j] - __uint_as_float((unsigned)g << 16));
            }
            const int sidx = lrow * 40 + lk0 + 4 * q;
            *(ushort4*)&Ah[sidx] = ah;
            *(ushort4*)&Al[sidx] = alo;
            *(ushort4*)&Bh[sidx] = bh;
            *(ushort4*)&Bl[sidx] = blo;
        }
        __syncthreads();

        s16x8 fah[4], fal[4], fbh[4], fbl[4];
#pragma unroll
        for (int i = 0; i < 4; ++i) {
            const int ar = (wm + i * 16 + fr) * 40 + fk;
            fah[i] = *(const s16x8*)&Ah[ar];
            fal[i] = *(const s16x8*)&Al[ar];
            const int br = (wn + i * 16 + fr) * 40 + fk;
            fbh[i] = *(const s16x8*)&Bh[br];
            fbl[i] = *(const s16x8*)&Bl[br];
        }
#pragma unroll
        for (int i = 0; i < 4; ++i)
#pragma unroll
            for (int j = 0; j < 4; ++j) {
                acc[i][j] = __builtin_amdgcn_mfma_f32_16x16x32_bf16(fah[i], fbh[j], acc[i][j], 0, 0, 0);
                acc[i][j] = __builtin_amdgcn_mfma_f32_16x16x32_bf16(fah[i], fbl[j], acc[i][j], 0, 0, 0);
                acc[i][j] = __builtin_amdgcn_mfma_f32_16x16x32_bf16(fal[i], fbh[j], acc[i][j], 0, 0, 0);
            }
        __syncthreads();
    }

    const int rbase = (lane >> 4) * 4;
#pragma unroll
    for (int j = 0; j < 4; ++j) {
        const int col = n0 + wn + j * 16 + fr;
        if (col >= N) continue;
        const float bb = bias1[col] + (bias2 ? bias2[col] : 0.f);
#pragma unroll
        for (int i = 0; i < 4; ++i) {
#pragma unroll
            for (int r = 0; r < 4; ++r) {
                const int row = m0 + wm + i * 16 + rbase + r;
                C[(size_t)row * N + col] = acc[i][j][r] + bb;
            }
        }
    }
}

// ---------------------------------------------------------------------------
// 1-term bf16 out-projection GEMM with XCD co-location swizzle (round-9,
// proven: tail 602->385us, absmax unchanged).
// ---------------------------------------------------------------------------
__global__ __launch_bounds__(256, 2)
void gemm_out1(const float* __restrict__ A, const float* __restrict__ B,
               const float* __restrict__ bias1,
               float* __restrict__ C, int M, int N, int K)
{
    const int d = blockIdx.x;
    const int xcd = d & 7;
    const int l   = d >> 3;
    const int p   = xcd + 8 * (l >> 2);   // N-panel index, p%8 == xcd
    const int mt  = l & 3;                // M-tile 0..3
    if (p >= (N + 127) / 128) return;
    const int m0 = mt * 128;
    const int n0 = p * 128;

    __shared__ unsigned short Ah[128 * 40];
    __shared__ unsigned short Bh[128 * 40];

    const int tid  = threadIdx.x;
    const int lrow = tid >> 1;
    const int lk0  = (tid & 1) << 4;
    const int lane = tid & 63;
    const int wave = tid >> 6;
    const int wm   = (wave >> 1) * 64;
    const int wn   = (wave & 1) * 64;
    const int fr   = lane & 15;
    const int fk   = (lane >> 4) * 8;

    f32x4 acc[4][4];
#pragma unroll
    for (int i = 0; i < 4; ++i)
#pragma unroll
        for (int j = 0; j < 4; ++j) acc[i][j] = (f32x4){0.f, 0.f, 0.f, 0.f};

    const bool bvalid = (n0 + lrow) < N;
    const float* pa = A + (size_t)(m0 + lrow) * K + lk0;
    const float* pb = bvalid ? (B + (size_t)(n0 + lrow) * K + lk0) : nullptr;

    for (int k0 = 0; k0 < K; k0 += 32) {
        float4 va[4], vb[4];
#pragma unroll
        for (int q = 0; q < 4; ++q) va[q] = *(const float4*)(pa + k0 + 4 * q);
        if (bvalid) {
#pragma unroll
            for (int q = 0; q < 4; ++q) vb[q] = *(const float4*)(pb + k0 + 4 * q);
        } else {
#pragma unroll
            for (int q = 0; q < 4; ++q) vb[q] = make_float4(0.f, 0.f, 0.f, 0.f);
        }

#pragma unroll
        for (int q = 0; q < 4; ++q) {
            const float av[4] = {va[q].x, va[q].y, va[q].z, va[q].w};
            const float bv[4] = {vb[q].x, vb[q].y, vb[q].z, vb[q].w};
            ushort4 ah, bh;
            unsigned short* ahp = (unsigned short*)&ah;
            unsigned short* bhp = (unsigned short*)&bh;
#pragma unroll
            for (int j = 0; j < 4; ++j) {
                ahp[j] = bf16_hi_rne(av[j]);
                bhp[j] = bf16_hi_rne(bv[j]);
            }
            const int sidx = lrow * 40 + lk0 + 4 * q;
            *(ushort4*)&Ah[sidx] = ah;
            *(ushort4*)&Bh[sidx] = bh;
        }
        __syncthreads();

        s16x8 fah[4], fbh[4];
#pragma unroll
        for (int i = 0; i < 4; ++i) {
            fah[i] = *(const s16x8*)&Ah[(wm + i * 16 + fr) * 40 + fk];
            fbh[i] = *(const s16x8*)&Bh[(wn + i * 16 + fr) * 40 + fk];
        }
#pragma unroll
        for (int i = 0; i < 4; ++i)
#pragma unroll
            for (int j = 0; j < 4; ++j)
                acc[i][j] = __builtin_amdgcn_mfma_f32_16x16x32_bf16(fah[i], fbh[j], acc[i][j], 0, 0, 0);
        __syncthreads();
    }

    const int rbase = (lane >> 4) * 4;
#pragma unroll
    for (int j = 0; j < 4; ++j) {
        const int col = n0 + wn + j * 16 + fr;
        if (col >= N) continue;
        const float bb = bias1[col];
#pragma unroll
        for (int i = 0; i < 4; ++i) {
#pragma unroll
            for (int r = 0; r < 4; ++r) {
                const int row = m0 + wm + i * 16 + rbase + r;
                C[(size_t)row * N + col] = acc[i][j][r] + bb;
            }
        }
    }
}

// ---------------------------------------------------------------------------
// Persistent sequential LSTM with TAGGED-VALUE RELAY (round-5 structure).
// Tail: 32 threads (all wave 0) compute one activation each (branchless
// sigma path; tanh(x)=2*sigma(2x)-1), write the activated value BACK to
// gates_s (LDS, same-wave ds ordering — no cross-lane shfl of divergently
// computed values, the round-10 bug), then 8 threads gather f/g/o from LDS
// and finalize c,h + publish. Critical path: 5 serial transcendentals -> 2.
// ---------------------------------------------------------------------------
__device__ __forceinline__ void tag_wait4(const u64* p0, const u64* p1,
                                          const u64* p2, const u64* p3,
                                          unsigned want, float* o)
{
    u64 a = __hip_atomic_load(p0, __ATOMIC_RELAXED, __HIP_MEMORY_SCOPE_AGENT);
    u64 b = __hip_atomic_load(p1, __ATOMIC_RELAXED, __HIP_MEMORY_SCOPE_AGENT);
    u64 c = __hip_atomic_load(p2, __ATOMIC_RELAXED, __HIP_MEMORY_SCOPE_AGENT);
    u64 d = __hip_atomic_load(p3, __ATOMIC_RELAXED, __HIP_MEMORY_SCOPE_AGENT);
    while (((unsigned)(a >> 32) != want) | ((unsigned)(b >> 32) != want) |
           ((unsigned)(c >> 32) != want) | ((unsigned)(d >> 32) != want)) {
        __builtin_amdgcn_s_sleep(1);
        a = __hip_atomic_load(p0, __ATOMIC_RELAXED, __HIP_MEMORY_SCOPE_AGENT);
        b = __hip_atomic_load(p1, __ATOMIC_RELAXED, __HIP_MEMORY_SCOPE_AGENT);
        c = __hip_atomic_load(p2, __ATOMIC_RELAXED, __HIP_MEMORY_SCOPE_AGENT);
        d = __hip_atomic_load(p3, __ATOMIC_RELAXED, __HIP_MEMORY_SCOPE_AGENT);
    }
    o[0] = __uint_as_float((unsigned)a);
    o[1] = __uint_as_float((unsigned)b);
    o[2] = __uint_as_float((unsigned)c);
    o[3] = __uint_as_float((unsigned)d);
}

#define W_LIST(F) F(0) F(1) F(2) F(3) F(4) F(5) F(6) F(7) F(8) F(9) F(10) F(11) \
  F(12) F(13) F(14) F(15) F(16) F(17) F(18) F(19) F(20) F(21) F(22) F(23) \
  F(24) F(25) F(26) F(27) F(28) F(29) F(30) F(31)
#define DECLW(I) f32x4 w##I;
#define LOADW(I) w##I = wp4[I];
#define PINW(I)  asm volatile("" : "+v"(w##I));

#define CHUNK(CH, WA, WB, WC, WD) do { \
    const f32x4 ha = *(const f32x4*)&h_s[hbase + (CH) * 16 + 0]; \
    const f32x4 hcb = *(const f32x4*)&h_s[hbase + (CH) * 16 + 4]; \
    const f32x4 hcc = *(const f32x4*)&h_s[hbase + (CH) * 16 + 8]; \
    const f32x4 hcd = *(const f32x4*)&h_s[hbase + (CH) * 16 + 12]; \
    p0 = fmaf(WA.x, ha.x, p0);  p0 = fmaf(WA.y, ha.y, p0); \
    p0 = fmaf(WA.z, ha.z, p0);  p0 = fmaf(WA.w, ha.w, p0); \
    p1 = fmaf(WB.x, hcb.x, p1); p1 = fmaf(WB.y, hcb.y, p1); \
    p1 = fmaf(WB.z, hcb.z, p1); p1 = fmaf(WB.w, hcb.w, p1); \
    p2 = fmaf(WC.x, hcc.x, p2); p2 = fmaf(WC.y, hcc.y, p2); \
    p2 = fmaf(WC.z, hcc.z, p2); p2 = fmaf(WC.w, hcc.w, p2); \
    p3 = fmaf(WD.x, hcd.x, p3); p3 = fmaf(WD.y, hcd.y, p3); \
    p3 = fmaf(WD.z, hcd.z, p3); p3 = fmaf(WD.w, hcd.w, p3); \
} while (0)

// One LSTM step. GS = version index of the INPUT h; T = index into XP.
#define STEP(XP, T, GS, LAST, STOREHD) do { \
    float xc = 0.f; \
    if (sub == 0) xc = (XP)[(size_t)(T) * NG + grow];  /* issue before spin */ \
    { \
        const u64* hsrc = hbq + ((GS) & 1) * NH; \
        float hv[4]; \
        tag_wait4(&hsrc[tid], &hsrc[tid + 512], &hsrc[tid + 1024], &hsrc[tid + 1536], \
                  (unsigned)((GS) + 1), hv); \
        h_s[tid          + ((tid          >> 7) << 2)] = hv[0]; \
        h_s[(tid +  512) + (((tid +  512) >> 7) << 2)] = hv[1]; \
        h_s[(tid + 1024) + (((tid + 1024) >> 7) << 2)] = hv[2]; \
        h_s[(tid + 1536) + (((tid + 1536) >> 7) << 2)] = hv[3]; \
    } \
    __syncthreads(); \
    float p0 = 0.f, p1 = 0.f, p2 = 0.f, p3 = 0.f; \
    CHUNK(0, w0, w1, w2, w3);     CHUNK(1, w4, w5, w6, w7); \
    CHUNK(2, w8, w9, w10, w11);   CHUNK(3, w12, w13, w14, w15); \
    CHUNK(4, w16, w17, w18, w19); CHUNK(5, w20, w21, w22, w23); \
    CHUNK(6, w24, w25, w26, w27); CHUNK(7, w28, w29, w30, w31); \
    float partial = (p0 + p1) + (p2 + p3); \
    partial += __shfl_xor(partial, 1); \
    partial += __shfl_xor(partial, 2); \
    partial += __shfl_xor(partial, 4); \
    partial += __shfl_xor(partial, 8); \
    if (sub == 0) gates_s[row] = partial + xc; \
    __syncthreads(); \
    if (tid < 32) { \
        const float xg  = gates_s[tid]; \
        const bool isg  = (tid & 24) == 16;          /* rows 16..23 = g-gate */ \
        const float xx  = isg ? xg + xg : xg; \
        const float s   = 1.f / (1.f + __expf(-xx)); \
        const float a   = isg ? s + s - 1.f : s;     /* sigma or tanh */ \
        gates_s[tid] = a;   /* same-wave LDS ordering: ds_write then ds_read */ \
        if (tid < 8) { \
            const float fg = gates_s[8 + tid]; \
            const float gg = gates_s[16 + tid]; \
            const float og = gates_s[24 + tid]; \
            const float cn = fg * c_s[tid] + a * gg; \
            c_s[tid] = cn; \
            const float th = 2.f / (1.f + __expf(-(cn + cn))) - 1.f; \
            const float hn = og * th; \
            if (STOREHD) Hd[(size_t)(T) * NH + wg * 8 + tid] = hn; \
            if (!(LAST)) { \
                const u64 pv = ((u64)(unsigned)((GS) + 2) << 32) | (u64)__float_as_uint(hn); \
                __hip_atomic_store(&hbq[(((GS) + 1) & 1) * NH + wg * 8 + tid], pv, \
                                   __ATOMIC_RELAXED, __HIP_MEMORY_SCOPE_AGENT); \
            } \
        } \
    } \
} while (0)

__global__ __launch_bounds__(512, 2)
void seq_lstm(const float* __restrict__ Whh_e,
              const float* __restrict__ Whh_d,
              const float* __restrict__ Xe,   // [LSEQ][NG]
              const float* __restrict__ Xd,   // [LSEQ][NG]
              u64* __restrict__ hbq,          // [2][NH] tagged h relay buffers
              float* __restrict__ Hd)         // [LSEQ][NH]
{
    const int wg   = blockIdx.x;
    const int tid  = threadIdx.x;
    const int lane = tid & 63;
    const int wv   = tid >> 6;
    const int row  = (wv << 2) + (lane >> 4);
    const int sub  = lane & 15;
    const int gate = row >> 3;
    const int u    = row & 7;
    const int grow = gate * NH + wg * 8 + u;
    const int hbase = sub * 132;

    __shared__ float h_s[2112];
    __shared__ float gates_s[32];
    __shared__ float c_s[8];

    W_LIST(DECLW)

    {
        const f32x4* wp4 = (const f32x4*)(Whh_e + (size_t)grow * NH + sub * 128);
        W_LIST(LOADW)
        W_LIST(PINW)
    }

    if (tid < 8) {
        c_s[tid] = 0.f;
        const u64 v0 = ((u64)1 << 32);
        __hip_atomic_store(&hbq[wg * 8 + tid], v0,
                           __ATOMIC_RELAXED, __HIP_MEMORY_SCOPE_AGENT);
    }
    __syncthreads();

#pragma unroll 1
    for (int t = 0; t < LSEQ; ++t) {
        STEP(Xe, t, t, false, false);
    }

    {
        const f32x4* wp4 = (const f32x4*)(Whh_d + (size_t)grow * NH + sub * 128);
        W_LIST(LOADW)
        W_LIST(PINW)
    }

#pragma unroll 1
    for (int t = 0; t < LSEQ; ++t) {
        STEP(Xd, t, LSEQ + t, (t == LSEQ - 1), true);
    }
}

// ---------------------------------------------------------------------------
extern "C" void kernel_launch(void* const* d_in, const int* in_sizes, int n_in,
                              void* d_out, int out_size, void* d_ws, size_t ws_size,
                              hipStream_t stream)
{
    const float* src   = (const float*)d_in[0];
    const float* tgt   = (const float*)d_in[1];
    const float* Wih_e = (const float*)d_in[2];
    const float* Whh_e = (const float*)d_in[3];
    const float* bih_e = (const float*)d_in[4];
    const float* bhh_e = (const float*)d_in[5];
    const float* Wih_d = (const float*)d_in[6];
    const float* Whh_d = (const float*)d_in[7];
    const float* bih_d = (const float*)d_in[8];
    const float* bhh_d = (const float*)d_in[9];
    const float* Wout  = (const float*)d_in[10];
    const float* bout  = (const float*)d_in[11];
    float* out = (float*)d_out;

    // workspace layout (bytes):
    //   [0, 32K)      hbq[2][2048] u64 tagged h relay (memset 0 each call)
    //   [32K, +4MB)   Hd[512][2048]
    //   [+, +16MB)    Xe[512][8192]
    //   [+, +16MB)    Xd[512][8192]
    char* ws = (char*)d_ws;
    u64*  hbq = (u64*)ws;
    float* Hd = (float*)(ws + 32768);
    float* Xe = (float*)(ws + 32768 + (size_t)LSEQ * NH * 4);
    float* Xd = Xe + (size_t)LSEQ * NG;

    hipMemsetAsync(ws, 0, 32768, stream);

    const dim3 blk(256);
    // input-side gate GEMMs: full 3-term split (errors feed the recurrence)
    gemm_x3<<<dim3(LSEQ / 128, NG / 128), blk, 0, stream>>>(
        src, Wih_e, bih_e, bhh_e, Xe, LSEQ, NG, NIN);
    gemm_x3<<<dim3(LSEQ / 128, NG / 128), blk, 0, stream>>>(
        tgt, Wih_d, bih_d, bhh_d, Xd, LSEQ, NG, NIN);

    seq_lstm<<<dim3(256), dim3(512), 0, stream>>>(
        Whh_e, Whh_d, Xe, Xd, hbq, Hd);

    // output projection: 1-term bf16 GEMM, XCD co-location swizzle.
    gemm_out1<<<dim3(1600), blk, 0, stream>>>(
        Hd, Wout, bout, out, LSEQ, NV, NH);
}

// Round 12
// 3052.433 us; speedup vs baseline: 1.0440x; 1.0440x over previous
//
#include <hip/hip_runtime.h>

#define LSEQ 512
#define NIN 1024
#define NH 2048
#define NV 50257
#define NG 8192  /* 4*NH */

typedef float f32x4 __attribute__((ext_vector_type(4)));
typedef short s16x8 __attribute__((ext_vector_type(8)));
typedef unsigned long long u64;

// ---------------------------------------------------------------------------
// fp32 -> bf16 RNE helper for the split-bf16 trick.
// ---------------------------------------------------------------------------
__device__ __forceinline__ unsigned short bf16_hi_rne(float x)
{
    unsigned u = __float_as_uint(x);
    return (unsigned short)((u + 0x7fffu + ((u >> 16) & 1u)) >> 16);
}

// ---------------------------------------------------------------------------
// 3-term split-bf16 MFMA GEMM (round-5 structure, proven):
// C = A@B^T + bias1 + bias2;  A.B ~= Ah.Bh + Ah.Bl + Al.Bh  (~fp32-class).
// ---------------------------------------------------------------------------
__global__ __launch_bounds__(256, 2)
void gemm_x3(const float* __restrict__ A, const float* __restrict__ B,
             const float* __restrict__ bias1, const float* __restrict__ bias2,
             float* __restrict__ C, int M, int N, int K)
{
    __shared__ unsigned short Ah[128 * 40], Al[128 * 40];
    __shared__ unsigned short Bh[128 * 40], Bl[128 * 40];

    const int tid  = threadIdx.x;
    const int m0   = blockIdx.x * 128;
    const int n0   = blockIdx.y * 128;
    const int lrow = tid >> 1;
    const int lk0  = (tid & 1) << 4;
    const int lane = tid & 63;
    const int wave = tid >> 6;
    const int wm   = (wave >> 1) * 64;
    const int wn   = (wave & 1) * 64;
    const int fr   = lane & 15;
    const int fk   = (lane >> 4) * 8;

    f32x4 acc[4][4];
#pragma unroll
    for (int i = 0; i < 4; ++i)
#pragma unroll
        for (int j = 0; j < 4; ++j) acc[i][j] = (f32x4){0.f, 0.f, 0.f, 0.f};

    const bool bvalid = (n0 + lrow) < N;
    const float* pa = A + (size_t)(m0 + lrow) * K + lk0;
    const float* pb = bvalid ? (B + (size_t)(n0 + lrow) * K + lk0) : nullptr;

    for (int k0 = 0; k0 < K; k0 += 32) {
        float4 va[4], vb[4];
#pragma unroll
        for (int q = 0; q < 4; ++q) va[q] = *(const float4*)(pa + k0 + 4 * q);
        if (bvalid) {
#pragma unroll
            for (int q = 0; q < 4; ++q) vb[q] = *(const float4*)(pb + k0 + 4 * q);
        } else {
#pragma unroll
            for (int q = 0; q < 4; ++q) vb[q] = make_float4(0.f, 0.f, 0.f, 0.f);
        }

#pragma unroll
        for (int q = 0; q < 4; ++q) {
            const float av[4] = {va[q].x, va[q].y, va[q].z, va[q].w};
            const float bv[4] = {vb[q].x, vb[q].y, vb[q].z, vb[q].w};
            ushort4 ah, alo, bh, blo;
            unsigned short* ahp = (unsigned short*)&ah;
            unsigned short* alp = (unsigned short*)&alo;
            unsigned short* bhp = (unsigned short*)&bh;
            unsigned short* blp = (unsigned short*)&blo;
#pragma unroll
            for (int j = 0; j < 4; ++j) {
                const unsigned short h = bf16_hi_rne(av[j]);
                ahp[j] = h;
                alp[j] = bf16_hi_rne(av[j] - __uint_as_float((unsigned)h << 16));
                const unsigned short g = bf16_hi_rne(bv[j]);
                bhp[j] = g;
                blp[j] = bf16_hi_rne(bv[j] - __uint_as_float((unsigned)g << 16));
            }
            const int sidx = lrow * 40 + lk0 + 4 * q;
            *(ushort4*)&Ah[sidx] = ah;
            *(ushort4*)&Al[sidx] = alo;
            *(ushort4*)&Bh[sidx] = bh;
            *(ushort4*)&Bl[sidx] = blo;
        }
        __syncthreads();

        s16x8 fah[4], fal[4], fbh[4], fbl[4];
#pragma unroll
        for (int i = 0; i < 4; ++i) {
            const int ar = (wm + i * 16 + fr) * 40 + fk;
            fah[i] = *(const s16x8*)&Ah[ar];
            fal[i] = *(const s16x8*)&Al[ar];
            const int br = (wn + i * 16 + fr) * 40 + fk;
            fbh[i] = *(const s16x8*)&Bh[br];
            fbl[i] = *(const s16x8*)&Bl[br];
        }
#pragma unroll
        for (int i = 0; i < 4; ++i)
#pragma unroll
            for (int j = 0; j < 4; ++j) {
                acc[i][j] = __builtin_amdgcn_mfma_f32_16x16x32_bf16(fah[i], fbh[j], acc[i][j], 0, 0, 0);
                acc[i][j] = __builtin_amdgcn_mfma_f32_16x16x32_bf16(fah[i], fbl[j], acc[i][j], 0, 0, 0);
                acc[i][j] = __builtin_amdgcn_mfma_f32_16x16x32_bf16(fal[i], fbh[j], acc[i][j], 0, 0, 0);
            }
        __syncthreads();
    }

    const int rbase = (lane >> 4) * 4;
#pragma unroll
    for (int j = 0; j < 4; ++j) {
        const int col = n0 + wn + j * 16 + fr;
        if (col >= N) continue;
        const float bb = bias1[col] + (bias2 ? bias2[col] : 0.f);
#pragma unroll
        for (int i = 0; i < 4; ++i) {
#pragma unroll
            for (int r = 0; r < 4; ++r) {
                const int row = m0 + wm + i * 16 + rbase + r;
                C[(size_t)row * N + col] = acc[i][j][r] + bb;
            }
        }
    }
}

// ---------------------------------------------------------------------------
// 1-term bf16 out-projection GEMM with XCD co-location swizzle (round-9,
// proven: tail 602->385us, absmax unchanged).
// ---------------------------------------------------------------------------
__global__ __launch_bounds__(256, 2)
void gemm_out1(const float* __restrict__ A, const float* __restrict__ B,
               const float* __restrict__ bias1,
               float* __restrict__ C, int M, int N, int K)
{
    const int d = blockIdx.x;
    const int xcd = d & 7;
    const int l   = d >> 3;
    const int p   = xcd + 8 * (l >> 2);   // N-panel index, p%8 == xcd
    const int mt  = l & 3;                // M-tile 0..3
    if (p >= (N + 127) / 128) return;
    const int m0 = mt * 128;
    const int n0 = p * 128;

    __shared__ unsigned short Ah[128 * 40];
    __shared__ unsigned short Bh[128 * 40];

    const int tid  = threadIdx.x;
    const int lrow = tid >> 1;
    const int lk0  = (tid & 1) << 4;
    const int lane = tid & 63;
    const int wave = tid >> 6;
    const int wm   = (wave >> 1) * 64;
    const int wn   = (wave & 1) * 64;
    const int fr   = lane & 15;
    const int fk   = (lane >> 4) * 8;

    f32x4 acc[4][4];
#pragma unroll
    for (int i = 0; i < 4; ++i)
#pragma unroll
        for (int j = 0; j < 4; ++j) acc[i][j] = (f32x4){0.f, 0.f, 0.f, 0.f};

    const bool bvalid = (n0 + lrow) < N;
    const float* pa = A + (size_t)(m0 + lrow) * K + lk0;
    const float* pb = bvalid ? (B + (size_t)(n0 + lrow) * K + lk0) : nullptr;

    for (int k0 = 0; k0 < K; k0 += 32) {
        float4 va[4], vb[4];
#pragma unroll
        for (int q = 0; q < 4; ++q) va[q] = *(const float4*)(pa + k0 + 4 * q);
        if (bvalid) {
#pragma unroll
            for (int q = 0; q < 4; ++q) vb[q] = *(const float4*)(pb + k0 + 4 * q);
        } else {
#pragma unroll
            for (int q = 0; q < 4; ++q) vb[q] = make_float4(0.f, 0.f, 0.f, 0.f);
        }

#pragma unroll
        for (int q = 0; q < 4; ++q) {
            const float av[4] = {va[q].x, va[q].y, va[q].z, va[q].w};
            const float bv[4] = {vb[q].x, vb[q].y, vb[q].z, vb[q].w};
            ushort4 ah, bh;
            unsigned short* ahp = (unsigned short*)&ah;
            unsigned short* bhp = (unsigned short*)&bh;
#pragma unroll
            for (int j = 0; j < 4; ++j) {
                ahp[j] = bf16_hi_rne(av[j]);
                bhp[j] = bf16_hi_rne(bv[j]);
            }
            const int sidx = lrow * 40 + lk0 + 4 * q;
            *(ushort4*)&Ah[sidx] = ah;
            *(ushort4*)&Bh[sidx] = bh;
        }
        __syncthreads();

        s16x8 fah[4], fbh[4];
#pragma unroll
        for (int i = 0; i < 4; ++i) {
            fah[i] = *(const s16x8*)&Ah[(wm + i * 16 + fr) * 40 + fk];
            fbh[i] = *(const s16x8*)&Bh[(wn + i * 16 + fr) * 40 + fk];
        }
#pragma unroll
        for (int i = 0; i < 4; ++i)
#pragma unroll
            for (int j = 0; j < 4; ++j)
                acc[i][j] = __builtin_amdgcn_mfma_f32_16x16x32_bf16(fah[i], fbh[j], acc[i][j], 0, 0, 0);
        __syncthreads();
    }

    const int rbase = (lane >> 4) * 4;
#pragma unroll
    for (int j = 0; j < 4; ++j) {
        const int col = n0 + wn + j * 16 + fr;
        if (col >= N) continue;
        const float bb = bias1[col];
#pragma unroll
        for (int i = 0; i < 4; ++i) {
#pragma unroll
            for (int r = 0; r < 4; ++r) {
                const int row = m0 + wm + i * 16 + rbase + r;
                C[(size_t)row * N + col] = acc[i][j][r] + bb;
            }
        }
    }
}

// ---------------------------------------------------------------------------
// Persistent sequential LSTM with TAGGED-VALUE RELAY — byte-identical to the
// round-5/8/9 kernel (2.66 ms verified, n=3): s_sleep(1) poll, one 64-bit
// atom per h value (tag<<32 | bits), relaxed agent-scope atomics, zero
// fences, serial 8-thread gate tail (measured faster than both parallel-tail
// variants: shfl version broke exec-mask semantics, LDS version +4.5%).
// ---------------------------------------------------------------------------
__device__ __forceinline__ float sigmoidf_(float x)
{
    return 1.f / (1.f + __expf(-x));
}

__device__ __forceinline__ void tag_wait4(const u64* p0, const u64* p1,
                                          const u64* p2, const u64* p3,
                                          unsigned want, float* o)
{
    u64 a = __hip_atomic_load(p0, __ATOMIC_RELAXED, __HIP_MEMORY_SCOPE_AGENT);
    u64 b = __hip_atomic_load(p1, __ATOMIC_RELAXED, __HIP_MEMORY_SCOPE_AGENT);
    u64 c = __hip_atomic_load(p2, __ATOMIC_RELAXED, __HIP_MEMORY_SCOPE_AGENT);
    u64 d = __hip_atomic_load(p3, __ATOMIC_RELAXED, __HIP_MEMORY_SCOPE_AGENT);
    while (((unsigned)(a >> 32) != want) | ((unsigned)(b >> 32) != want) |
           ((unsigned)(c >> 32) != want) | ((unsigned)(d >> 32) != want)) {
        __builtin_amdgcn_s_sleep(1);
        a = __hip_atomic_load(p0, __ATOMIC_RELAXED, __HIP_MEMORY_SCOPE_AGENT);
        b = __hip_atomic_load(p1, __ATOMIC_RELAXED, __HIP_MEMORY_SCOPE_AGENT);
        c = __hip_atomic_load(p2, __ATOMIC_RELAXED, __HIP_MEMORY_SCOPE_AGENT);
        d = __hip_atomic_load(p3, __ATOMIC_RELAXED, __HIP_MEMORY_SCOPE_AGENT);
    }
    o[0] = __uint_as_float((unsigned)a);
    o[1] = __uint_as_float((unsigned)b);
    o[2] = __uint_as_float((unsigned)c);
    o[3] = __uint_as_float((unsigned)d);
}

#define W_LIST(F) F(0) F(1) F(2) F(3) F(4) F(5) F(6) F(7) F(8) F(9) F(10) F(11) \
  F(12) F(13) F(14) F(15) F(16) F(17) F(18) F(19) F(20) F(21) F(22) F(23) \
  F(24) F(25) F(26) F(27) F(28) F(29) F(30) F(31)
#define DECLW(I) f32x4 w##I;
#define LOADW(I) w##I = wp4[I];
#define PINW(I)  asm volatile("" : "+v"(w##I));

#define CHUNK(CH, WA, WB, WC, WD) do { \
    const f32x4 ha = *(const f32x4*)&h_s[hbase + (CH) * 16 + 0]; \
    const f32x4 hcb = *(const f32x4*)&h_s[hbase + (CH) * 16 + 4]; \
    const f32x4 hcc = *(const f32x4*)&h_s[hbase + (CH) * 16 + 8]; \
    const f32x4 hcd = *(const f32x4*)&h_s[hbase + (CH) * 16 + 12]; \
    p0 = fmaf(WA.x, ha.x, p0);  p0 = fmaf(WA.y, ha.y, p0); \
    p0 = fmaf(WA.z, ha.z, p0);  p0 = fmaf(WA.w, ha.w, p0); \
    p1 = fmaf(WB.x, hcb.x, p1); p1 = fmaf(WB.y, hcb.y, p1); \
    p1 = fmaf(WB.z, hcb.z, p1); p1 = fmaf(WB.w, hcb.w, p1); \
    p2 = fmaf(WC.x, hcc.x, p2); p2 = fmaf(WC.y, hcc.y, p2); \
    p2 = fmaf(WC.z, hcc.z, p2); p2 = fmaf(WC.w, hcc.w, p2); \
    p3 = fmaf(WD.x, hcd.x, p3); p3 = fmaf(WD.y, hcd.y, p3); \
    p3 = fmaf(WD.z, hcd.z, p3); p3 = fmaf(WD.w, hcd.w, p3); \
} while (0)

// One LSTM step. GS = version index of the INPUT h; T = index into XP.
#define STEP(XP, T, GS, LAST, STOREHD) do { \
    float xc = 0.f; \
    if (sub == 0) xc = (XP)[(size_t)(T) * NG + grow];  /* issue before spin */ \
    { \
        const u64* hsrc = hbq + ((GS) & 1) * NH; \
        float hv[4]; \
        tag_wait4(&hsrc[tid], &hsrc[tid + 512], &hsrc[tid + 1024], &hsrc[tid + 1536], \
                  (unsigned)((GS) + 1), hv); \
        h_s[tid          + ((tid          >> 7) << 2)] = hv[0]; \
        h_s[(tid +  512) + (((tid +  512) >> 7) << 2)] = hv[1]; \
        h_s[(tid + 1024) + (((tid + 1024) >> 7) << 2)] = hv[2]; \
        h_s[(tid + 1536) + (((tid + 1536) >> 7) << 2)] = hv[3]; \
    } \
    __syncthreads(); \
    float p0 = 0.f, p1 = 0.f, p2 = 0.f, p3 = 0.f; \
    CHUNK(0, w0, w1, w2, w3);     CHUNK(1, w4, w5, w6, w7); \
    CHUNK(2, w8, w9, w10, w11);   CHUNK(3, w12, w13, w14, w15); \
    CHUNK(4, w16, w17, w18, w19); CHUNK(5, w20, w21, w22, w23); \
    CHUNK(6, w24, w25, w26, w27); CHUNK(7, w28, w29, w30, w31); \
    float partial = (p0 + p1) + (p2 + p3); \
    partial += __shfl_xor(partial, 1); \
    partial += __shfl_xor(partial, 2); \
    partial += __shfl_xor(partial, 4); \
    partial += __shfl_xor(partial, 8); \
    if (sub == 0) gates_s[row] = partial + xc; \
    __syncthreads(); \
    if (tid < 8) { \
        const float ig = sigmoidf_(gates_s[tid]); \
        const float fg = sigmoidf_(gates_s[8 + tid]); \
        const float gg = tanhf(gates_s[16 + tid]); \
        const float og = sigmoidf_(gates_s[24 + tid]); \
        const float cn = fg * c_s[tid] + ig * gg; \
        c_s[tid] = cn; \
        const float hn = og * tanhf(cn); \
        if (STOREHD) Hd[(size_t)(T) * NH + wg * 8 + tid] = hn; \
        if (!(LAST)) { \
            const u64 pv = ((u64)(unsigned)((GS) + 2) << 32) | (u64)__float_as_uint(hn); \
            __hip_atomic_store(&hbq[(((GS) + 1) & 1) * NH + wg * 8 + tid], pv, \
                               __ATOMIC_RELAXED, __HIP_MEMORY_SCOPE_AGENT); \
        } \
    } \
} while (0)

__global__ __launch_bounds__(512, 2)
void seq_lstm(const float* __restrict__ Whh_e,
              const float* __restrict__ Whh_d,
              const float* __restrict__ Xe,   // [LSEQ][NG]
              const float* __restrict__ Xd,   // [LSEQ][NG]
              u64* __restrict__ hbq,          // [2][NH] tagged h relay buffers
              float* __restrict__ Hd)         // [LSEQ][NH]
{
    const int wg   = blockIdx.x;
    const int tid  = threadIdx.x;
    const int lane = tid & 63;
    const int wv   = tid >> 6;
    const int row  = (wv << 2) + (lane >> 4);
    const int sub  = lane & 15;
    const int gate = row >> 3;
    const int u    = row & 7;
    const int grow = gate * NH + wg * 8 + u;
    const int hbase = sub * 132;

    __shared__ float h_s[2112];
    __shared__ float gates_s[32];
    __shared__ float c_s[8];

    W_LIST(DECLW)

    {
        const f32x4* wp4 = (const f32x4*)(Whh_e + (size_t)grow * NH + sub * 128);
        W_LIST(LOADW)
        W_LIST(PINW)
    }

    if (tid < 8) {
        c_s[tid] = 0.f;
        const u64 v0 = ((u64)1 << 32);
        __hip_atomic_store(&hbq[wg * 8 + tid], v0,
                           __ATOMIC_RELAXED, __HIP_MEMORY_SCOPE_AGENT);
    }
    __syncthreads();

#pragma unroll 1
    for (int t = 0; t < LSEQ; ++t) {
        STEP(Xe, t, t, false, false);
    }

    {
        const f32x4* wp4 = (const f32x4*)(Whh_d + (size_t)grow * NH + sub * 128);
        W_LIST(LOADW)
        W_LIST(PINW)
    }

#pragma unroll 1
    for (int t = 0; t < LSEQ; ++t) {
        STEP(Xd, t, LSEQ + t, (t == LSEQ - 1), true);
    }
}

// ---------------------------------------------------------------------------
extern "C" void kernel_launch(void* const* d_in, const int* in_sizes, int n_in,
                              void* d_out, int out_size, void* d_ws, size_t ws_size,
                              hipStream_t stream)
{
    const float* src   = (const float*)d_in[0];
    const float* tgt   = (const float*)d_in[1];
    const float* Wih_e = (const float*)d_in[2];
    const float* Whh_e = (const float*)d_in[3];
    const float* bih_e = (const float*)d_in[4];
    const float* bhh_e = (const float*)d_in[5];
    const float* Wih_d = (const float*)d_in[6];
    const float* Whh_d = (const float*)d_in[7];
    const float* bih_d = (const float*)d_in[8];
    const float* bhh_d = (const float*)d_in[9];
    const float* Wout  = (const float*)d_in[10];
    const float* bout  = (const float*)d_in[11];
    float* out = (float*)d_out;

    // workspace layout (bytes):
    //   [0, 32K)      hbq[2][2048] u64 tagged h relay (memset 0 each call)
    //   [32K, +4MB)   Hd[512][2048]
    //   [+, +16MB)    Xe[512][8192]
    //   [+, +16MB)    Xd[512][8192]
    char* ws = (char*)d_ws;
    u64*  hbq = (u64*)ws;
    float* Hd = (float*)(ws + 32768);
    float* Xe = (float*)(ws + 32768 + (size_t)LSEQ * NH * 4);
    float* Xd = Xe + (size_t)LSEQ * NG;

    hipMemsetAsync(ws, 0, 32768, stream);

    const dim3 blk(256);
    // input-side gate GEMMs: full 3-term split (errors feed the recurrence)
    gemm_x3<<<dim3(LSEQ / 128, NG / 128), blk, 0, stream>>>(
        src, Wih_e, bih_e, bhh_e, Xe, LSEQ, NG, NIN);
    gemm_x3<<<dim3(LSEQ / 128, NG / 128), blk, 0, stream>>>(
        tgt, Wih_d, bih_d, bhh_d, Xd, LSEQ, NG, NIN);

    seq_lstm<<<dim3(256), dim3(512), 0, stream>>>(
        Whh_e, Whh_d, Xe, Xd, hbq, Hd);

    // output projection: 1-term bf16 GEMM, XCD co-location swizzle.
    gemm_out1<<<dim3(1600), blk, 0, stream>>>(
        Hd, Wout, bout, out, LSEQ, NV, NH);
}